// Round 14
// baseline (626.674 us; speedup 1.0000x reference)
//
#include <hip/hip_runtime.h>

#define V 196608
#define NNZ (9 * V)
#define B 4
#define FIN 32
#define FOUT 64
#define K 5
#define C 128            // FIN*B feature columns per vertex
#define ROWU 64          // uints per bf16 row (128 feats * 2B / 4B)
#define SPMM_BLOCKS 2048 // persistent grid: 8 blocks/CU * 256 CU
#define NSLICE 864       // edge slices; NNZ = 864 * 2048 exactly
#define EDGES_PER_SLICE 2048
#define HIST_BLOCKS (NSLICE * 8)   // 6912: slice x 8 XCD-windows
#define X0_BLOCKS (V * 16 / 256)   // 12288
#define WFRAG_BLOCKS 5

typedef __attribute__((ext_vector_type(8))) short bf16x8;
typedef __attribute__((ext_vector_type(4))) float f32x4;

// ---- bf16 helpers (bit-level, RNE) ---------------------------------------
static __device__ __forceinline__ unsigned int f2bf(float f) {
    union { float f; unsigned int u; } v; v.f = f;
    return (v.u + 0x7FFFu + ((v.u >> 16) & 1u)) >> 16;
}
static __device__ __forceinline__ float bflo(unsigned int u) {
    union { unsigned int u; float f; } v; v.u = u << 16; return v.f;
}
static __device__ __forceinline__ float bfhi(unsigned int u) {
    union { unsigned int u; float f; } v; v.u = u & 0xFFFF0000u; return v.f;
}

// ---------------------------------------------------------------------------
// fast zero for cnt: V ints = 48K uint4
__global__ void zero_cursor(uint4* __restrict__ p) {
    int t = blockIdx.x * 256 + threadIdx.x;
    if (t < V / 4) p[t] = (uint4){0u, 0u, 0u, 0u};
}

// ---------------------------------------------------------------------------
// FUSED prep. Hist part is XCD-WINDOWED: block b covers edge slice b>>3 and
// only atomics rows in window (b&7)*V/8..+V/8. All RMWs on a counter line
// come from one blockIdx%8 class (= one XCD) -> line stays in that L2, no
// cross-XCD ownership bounce to HBM (r13 counter evidence: 111MB WRITE_SIZE
// == 53MB of bounced atomic lines). Tail blocks: x0 transpose + W frags.
__global__ void prep_fused(const int* __restrict__ rows, int* __restrict__ cnt,
                           int* __restrict__ rank, const float* __restrict__ inp,
                           uint4* __restrict__ x0v, const float* __restrict__ w,
                           uint4* __restrict__ wfh, uint4* __restrict__ wfl) {
    const int blk = blockIdx.x;
    if (blk < HIST_BLOCKS) {
        // ---- XCD-windowed histogram + per-edge rank ----
        const int slice = blk >> 3;
        const int win = blk & 7;
        const int lo = win * (V / 8);
        const int hi = lo + (V / 8);
        const int base = slice * EDGES_PER_SLICE;
#pragma unroll 2
        for (int i = threadIdx.x; i < EDGES_PER_SLICE; i += 256) {
            int e = base + i;
            int r = rows[e];
            if (r >= lo && r < hi) rank[e] = atomicAdd(&cnt[r], 1);
        }
    } else if (blk < HIST_BLOCKS + X0_BLOCKS) {
        // ---- x0[v][b*32+fin] bf16 b-major; thread = one uint4 (8 feats) ----
        int t = (blk - HIST_BLOCKS) * 256 + threadIdx.x;  // < V*16 exactly
        int v = t >> 4;
        int seg = t & 15;
        int b = seg >> 2;
        int q = seg & 3;
        const float4* s =
            reinterpret_cast<const float4*>(inp + ((size_t)b * V + v) * 32 + q * 8);
        float4 fa = s[0], fb = s[1];
        uint4 u;
        u.x = f2bf(fa.x) | (f2bf(fa.y) << 16);
        u.y = f2bf(fa.z) | (f2bf(fa.w) << 16);
        u.z = f2bf(fb.x) | (f2bf(fb.y) << 16);
        u.w = f2bf(fb.z) | (f2bf(fb.w) << 16);
        x0v[(size_t)v * 16 + seg] = u;
    } else {
        // ---- W fragments: split-precision bf16 B-frags, k-major ----
        int idx = (blk - HIST_BLOCKS - X0_BLOCKS) * 256 + threadIdx.x;
        if (idx >= K * 4 * 64) return;
        int lane = idx & 63;
        int nt = (idx >> 6) & 3;
        int k = idx >> 8;
        int col = lane & 15;
        int quad = lane >> 4;
        int o = nt * 16 + col;
        unsigned int hh[8], ll[8];
#pragma unroll
        for (int e = 0; e < 8; ++e) {
            int fin = quad * 8 + e;
            float wv = w[(fin * 5 + k) * 64 + o];
            unsigned int hb = f2bf(wv);
            float hf = bflo(hb);
            ll[e] = f2bf(wv - hf);
            hh[e] = hb;
        }
        uint4 uh, ul;
        uh.x = hh[0] | (hh[1] << 16);
        uh.y = hh[2] | (hh[3] << 16);
        uh.z = hh[4] | (hh[5] << 16);
        uh.w = hh[6] | (hh[7] << 16);
        ul.x = ll[0] | (ll[1] << 16);
        ul.y = ll[2] | (ll[3] << 16);
        ul.z = ll[4] | (ll[5] << 16);
        ul.w = ll[6] | (ll[7] << 16);
        wfh[idx] = uh;
        wfl[idx] = ul;
    }
}

// ---------------------------------------------------------------------------
// parallel scan phase A: per-1024-chunk sums
__global__ void chunk_sums(const int* __restrict__ cnt, int* __restrict__ bsum) {
    __shared__ int ws[16];
    int tid = threadIdx.x;
    int lane = tid & 63;
    int wid = tid >> 6;
    int v = cnt[blockIdx.x * 1024 + tid];
#pragma unroll
    for (int off = 32; off >= 1; off >>= 1) v += __shfl_down(v, off, 64);
    if (lane == 0) ws[wid] = v;
    __syncthreads();
    if (tid < 16) {
        int s = ws[tid];
#pragma unroll
        for (int off = 8; off >= 1; off >>= 1) s += __shfl_down(s, off, 16);
        if (tid == 0) bsum[blockIdx.x] = s;
    }
}

// ---------------------------------------------------------------------------
// scan phase B+C fused: every block scans the 192 chunk sums in LDS, then
// does its per-chunk scan with the block prefix -> rowptr.
__global__ void scan_chunks2(const int* __restrict__ cnt, const int* __restrict__ bsum,
                             int* __restrict__ rowptr) {
    __shared__ int sb[192];
    __shared__ int wsum[16];
    int tid = threadIdx.x;
    int lane = tid & 63;
    int wid = tid >> 6;
    if (tid < 192) sb[tid] = bsum[tid];
    __syncthreads();
    for (int off = 1; off < 192; off <<= 1) {
        int v = (tid < 192 && tid >= off) ? sb[tid - off] : 0;
        __syncthreads();
        if (tid < 192) sb[tid] += v;
        __syncthreads();
    }
    const int bpre = (blockIdx.x == 0) ? 0 : sb[blockIdx.x - 1];
    int base = blockIdx.x * 1024;
    int v = cnt[base + tid];
    int x = v;
#pragma unroll
    for (int off = 1; off < 64; off <<= 1) {
        int t = __shfl_up(x, off, 64);
        if (lane >= off) x += t;
    }
    if (lane == 63) wsum[wid] = x;
    __syncthreads();
    if (wid == 0 && lane < 16) {
        int s = wsum[lane];
        int y = s;
#pragma unroll
        for (int off = 1; off < 16; off <<= 1) {
            int t = __shfl_up(y, off, 16);
            if (lane >= off) y += t;
        }
        wsum[lane] = y - s;
    }
    __syncthreads();
    int excl = x - v + wsum[wid] + bpre;
    rowptr[base + tid] = excl;
    if (blockIdx.x == 191 && tid == 1023) rowptr[V] = excl + v;
}

// ---------------------------------------------------------------------------
// XCD-partitioned rank scatter: block b handles edge slice b>>3, writes only
// positions in window (b&7) of cev. No atomics.
__global__ void scatter_rank(const int* __restrict__ rows, const int* __restrict__ cols,
                             const float* __restrict__ vals, const int* __restrict__ rowptr,
                             const int* __restrict__ rank, int2* __restrict__ cev) {
    const int slice = blockIdx.x >> 3;
    const int w = blockIdx.x & 7;
    const int lo = w * (NNZ / 8);
    const int hi = lo + (NNZ / 8);
    const int base = slice * EDGES_PER_SLICE;
#pragma unroll 2
    for (int i = threadIdx.x; i < EDGES_PER_SLICE; i += 256) {
        int e = base + i;
        int p = rowptr[rows[e]] + rank[e];
        if (p >= lo && p < hi) {
            int2 pk;
            pk.x = cols[e];
            pk.y = __float_as_int(vals[e]);
            cev[p] = pk;
        }
    }
}

// ---------------------------------------------------------------------------
// bf16 gather SpMM v3.1: persistent waves, 2 rows per iteration, joint 4+4
// strip-mine (8 gathers in flight), then solo 4-strips before 2/1 drains.
template <int COMBINE>
__global__ __launch_bounds__(256) void spmm_gather(
    const int* __restrict__ rowptr, const int2* __restrict__ cev,
    const unsigned int* __restrict__ x, const unsigned int* __restrict__ xm2,
    unsigned int* __restrict__ y) {
    const int lane = threadIdx.x & 63;
    const int wid0 = (blockIdx.x * 256 + threadIdx.x) >> 6;
    const int NW = SPMM_BLOCKS * 4;  // total waves
    for (int base = wid0 * 2; base < V; base += NW * 2) {
        const int r0 = base, r1 = base + 1;
        const int s0 = rowptr[r0];
        const int e0 = rowptr[r0 + 1];
        const int e1 = rowptr[r1 + 1];  // s1 == e0
        float ax0 = 0.f, ay0 = 0.f, ax1 = 0.f, ay1 = 0.f;
        int i0 = s0, i1 = e0;
        while (e0 - i0 >= 4 && e1 - i1 >= 4) {
            int2 Ea[4], Eb[4];
#pragma unroll
            for (int j = 0; j < 4; ++j) {
                Ea[j] = cev[i0 + j];
                Eb[j] = cev[i1 + j];
            }
            unsigned int Ua[4], Ub[4];
#pragma unroll
            for (int j = 0; j < 4; ++j) {
                Ua[j] = x[(size_t)Ea[j].x * ROWU + lane];
                Ub[j] = x[(size_t)Eb[j].x * ROWU + lane];
            }
#pragma unroll
            for (int j = 0; j < 4; ++j) {
                float va = __int_as_float(Ea[j].y);
                float vb = __int_as_float(Eb[j].y);
                ax0 = fmaf(va, bflo(Ua[j]), ax0);
                ay0 = fmaf(va, bfhi(Ua[j]), ay0);
                ax1 = fmaf(vb, bflo(Ub[j]), ax1);
                ay1 = fmaf(vb, bfhi(Ub[j]), ay1);
            }
            i0 += 4;
            i1 += 4;
        }
        while (e0 - i0 >= 4) {
            int2 Ea[4];
#pragma unroll
            for (int j = 0; j < 4; ++j) Ea[j] = cev[i0 + j];
            unsigned int Ua[4];
#pragma unroll
            for (int j = 0; j < 4; ++j) Ua[j] = x[(size_t)Ea[j].x * ROWU + lane];
#pragma unroll
            for (int j = 0; j < 4; ++j) {
                float va = __int_as_float(Ea[j].y);
                ax0 = fmaf(va, bflo(Ua[j]), ax0);
                ay0 = fmaf(va, bfhi(Ua[j]), ay0);
            }
            i0 += 4;
        }
        while (e1 - i1 >= 4) {
            int2 Eb[4];
#pragma unroll
            for (int j = 0; j < 4; ++j) Eb[j] = cev[i1 + j];
            unsigned int Ub[4];
#pragma unroll
            for (int j = 0; j < 4; ++j) Ub[j] = x[(size_t)Eb[j].x * ROWU + lane];
#pragma unroll
            for (int j = 0; j < 4; ++j) {
                float vb = __int_as_float(Eb[j].y);
                ax1 = fmaf(vb, bflo(Ub[j]), ax1);
                ay1 = fmaf(vb, bfhi(Ub[j]), ay1);
            }
            i1 += 4;
        }
        for (; i0 + 2 <= e0; i0 += 2) {
            int2 a = cev[i0], b = cev[i0 + 1];
            unsigned int u0 = x[(size_t)a.x * ROWU + lane];
            unsigned int u1 = x[(size_t)b.x * ROWU + lane];
            float v0 = __int_as_float(a.y), v1 = __int_as_float(b.y);
            ax0 = fmaf(v0, bflo(u0), ax0);
            ay0 = fmaf(v0, bfhi(u0), ay0);
            ax0 = fmaf(v1, bflo(u1), ax0);
            ay0 = fmaf(v1, bfhi(u1), ay0);
        }
        for (; i0 < e0; ++i0) {
            int2 a = cev[i0];
            unsigned int u = x[(size_t)a.x * ROWU + lane];
            float v = __int_as_float(a.y);
            ax0 = fmaf(v, bflo(u), ax0);
            ay0 = fmaf(v, bfhi(u), ay0);
        }
        for (; i1 + 2 <= e1; i1 += 2) {
            int2 a = cev[i1], b = cev[i1 + 1];
            unsigned int u0 = x[(size_t)a.x * ROWU + lane];
            unsigned int u1 = x[(size_t)b.x * ROWU + lane];
            float v0 = __int_as_float(a.y), v1 = __int_as_float(b.y);
            ax1 = fmaf(v0, bflo(u0), ax1);
            ay1 = fmaf(v0, bfhi(u0), ay1);
            ax1 = fmaf(v1, bflo(u1), ax1);
            ay1 = fmaf(v1, bfhi(u1), ay1);
        }
        for (; i1 < e1; ++i1) {
            int2 a = cev[i1];
            unsigned int u = x[(size_t)a.x * ROWU + lane];
            float v = __int_as_float(a.y);
            ax1 = fmaf(v, bflo(u), ax1);
            ay1 = fmaf(v, bfhi(u), ay1);
        }
        if (COMBINE) {
            unsigned int m0 = xm2[(size_t)r0 * ROWU + lane];
            unsigned int m1 = xm2[(size_t)r1 * ROWU + lane];
            ax0 = 2.0f * ax0 - bflo(m0);
            ay0 = 2.0f * ay0 - bfhi(m0);
            ax1 = 2.0f * ax1 - bflo(m1);
            ay1 = 2.0f * ay1 - bfhi(m1);
        }
        y[(size_t)r0 * ROWU + lane] = f2bf(ax0) | (f2bf(ay0) << 16);
        y[(size_t)r1 * ROWU + lane] = f2bf(ax1) | (f2bf(ay1) << 16);
    }
}

// ---------------------------------------------------------------------------
// MFMA fused output contraction. Wave = 16 vertices x 64 outs x 4 batches.
// A-frag: lane l holds x[v0+(l&15)][b*32 + (l>>4)*8 .. +8]  (one 16B load)
// C/D:    col=lane&15, row=(lane>>4)*4+reg   [m89-verified mapping]
__global__ __launch_bounds__(256) void fused_mfma(
    const unsigned short* __restrict__ x0, const unsigned short* __restrict__ x1,
    const unsigned short* __restrict__ x2, const unsigned short* __restrict__ x3,
    const unsigned short* __restrict__ x4, const uint4* __restrict__ wfh,
    const uint4* __restrict__ wfl, const float* __restrict__ bias,
    float* __restrict__ out) {
    const int tid = threadIdx.x;
    const int lane = tid & 63;
    const int g = (blockIdx.x * 256 + tid) >> 6;
    const int v0 = g << 4;
    const int col = lane & 15;
    const int quad = lane >> 4;
    const unsigned short* const xs[K] = {x0, x1, x2, x3, x4};

    f32x4 acc[B][4];
#pragma unroll
    for (int b = 0; b < B; ++b)
#pragma unroll
        for (int nt = 0; nt < 4; ++nt) acc[b][nt] = (f32x4){0.f, 0.f, 0.f, 0.f};

#pragma unroll
    for (int k = 0; k < K; ++k) {
        const unsigned short* xk = xs[k] + ((size_t)(v0 + col)) * C + quad * 8;
        bf16x8 a0 = *reinterpret_cast<const bf16x8*>(xk);
        bf16x8 a1 = *reinterpret_cast<const bf16x8*>(xk + 32);
        bf16x8 a2 = *reinterpret_cast<const bf16x8*>(xk + 64);
        bf16x8 a3 = *reinterpret_cast<const bf16x8*>(xk + 96);
#pragma unroll
        for (int nt = 0; nt < 4; ++nt) {
            uint4 uh = wfh[(k * 4 + nt) * 64 + lane];
            uint4 ul = wfl[(k * 4 + nt) * 64 + lane];
            bf16x8 wh = *reinterpret_cast<bf16x8*>(&uh);
            bf16x8 wl = *reinterpret_cast<bf16x8*>(&ul);
            acc[0][nt] = __builtin_amdgcn_mfma_f32_16x16x32_bf16(a0, wh, acc[0][nt], 0, 0, 0);
            acc[1][nt] = __builtin_amdgcn_mfma_f32_16x16x32_bf16(a1, wh, acc[1][nt], 0, 0, 0);
            acc[2][nt] = __builtin_amdgcn_mfma_f32_16x16x32_bf16(a2, wh, acc[2][nt], 0, 0, 0);
            acc[3][nt] = __builtin_amdgcn_mfma_f32_16x16x32_bf16(a3, wh, acc[3][nt], 0, 0, 0);
            acc[0][nt] = __builtin_amdgcn_mfma_f32_16x16x32_bf16(a0, wl, acc[0][nt], 0, 0, 0);
            acc[1][nt] = __builtin_amdgcn_mfma_f32_16x16x32_bf16(a1, wl, acc[1][nt], 0, 0, 0);
            acc[2][nt] = __builtin_amdgcn_mfma_f32_16x16x32_bf16(a2, wl, acc[2][nt], 0, 0, 0);
            acc[3][nt] = __builtin_amdgcn_mfma_f32_16x16x32_bf16(a3, wl, acc[3][nt], 0, 0, 0);
        }
    }

    float bv[4];
#pragma unroll
    for (int nt = 0; nt < 4; ++nt) bv[nt] = bias[nt * 16 + col];
#pragma unroll
    for (int b = 0; b < B; ++b)
#pragma unroll
        for (int nt = 0; nt < 4; ++nt)
#pragma unroll
            for (int r = 0; r < 4; ++r) {
                int row = quad * 4 + r;
                out[((size_t)b * V + v0 + row) * FOUT + nt * 16 + col] = acc[b][nt][r] + bv[nt];
            }
}

// ---------------------------------------------------------------------------
extern "C" void kernel_launch(void* const* d_in, const int* in_sizes, int n_in,
                              void* d_out, int out_size, void* d_ws, size_t ws_size,
                              hipStream_t stream) {
    const int* lap_rows = (const int*)d_in[0];
    const int* lap_cols = (const int*)d_in[1];
    const float* lap_vals = (const float*)d_in[2];
    const float* inputs = (const float*)d_in[3];
    const float* weight = (const float*)d_in[4];  // flat [160][64] == effective W
    const float* bias = (const float*)d_in[5];
    float* out = (float*)d_out;

    char* p = (char*)d_ws;
    auto alloc = [&](size_t bytes) {
        char* r = p;
        p += (bytes + 511) & ~(size_t)511;
        return r;
    };
    int* rowptr = (int*)alloc((size_t)(V + 1) * 4);
    int* cnt = (int*)alloc((size_t)V * 4);
    int* bsum = (int*)alloc(192 * 4);
    int* rank = (int*)alloc((size_t)NNZ * 4);
    uint4* wfh = (uint4*)alloc((size_t)K * 4 * 64 * 16);
    uint4* wfl = (uint4*)alloc((size_t)K * 4 * 64 * 16);
    int2* cev = (int2*)alloc((size_t)NNZ * 8);
    unsigned int* xb0 = (unsigned int*)alloc((size_t)V * ROWU * 4);
    unsigned int* xb1 = (unsigned int*)alloc((size_t)V * ROWU * 4);
    unsigned int* xb2 = (unsigned int*)alloc((size_t)V * ROWU * 4);
    unsigned int* xb3 = (unsigned int*)alloc((size_t)V * ROWU * 4);
    unsigned int* xb4 = (unsigned int*)alloc((size_t)V * ROWU * 4);

    const int mfma_blocks = (V / 16) * 64 / 256; // 3072
    const int prep_blocks = HIST_BLOCKS + X0_BLOCKS + WFRAG_BLOCKS;  // 19205

    // ---- CSR build + prep ----
    zero_cursor<<<(V / 4 + 255) / 256, 256, 0, stream>>>((uint4*)cnt);
    prep_fused<<<prep_blocks, 256, 0, stream>>>(lap_rows, cnt, rank, inputs, (uint4*)xb0,
                                                weight, wfh, wfl);
    chunk_sums<<<V / 1024, 1024, 0, stream>>>(cnt, bsum);
    scan_chunks2<<<V / 1024, 1024, 0, stream>>>(cnt, bsum, rowptr);
    scatter_rank<<<NSLICE * 8, 256, 0, stream>>>(lap_rows, lap_cols, lap_vals, rowptr,
                                                 rank, cev);

    // ---- Chebyshev recurrence (bf16 storage, f32 accumulate) ----
    spmm_gather<0><<<SPMM_BLOCKS, 256, 0, stream>>>(rowptr, cev, xb0, nullptr, xb1);
    spmm_gather<1><<<SPMM_BLOCKS, 256, 0, stream>>>(rowptr, cev, xb1, xb0, xb2);
    spmm_gather<1><<<SPMM_BLOCKS, 256, 0, stream>>>(rowptr, cev, xb2, xb1, xb3);
    spmm_gather<1><<<SPMM_BLOCKS, 256, 0, stream>>>(rowptr, cev, xb3, xb2, xb4);

    // ---- fused MFMA output contraction ----
    fused_mfma<<<mfma_blocks, 256, 0, stream>>>(
        (const unsigned short*)xb0, (const unsigned short*)xb1, (const unsigned short*)xb2,
        (const unsigned short*)xb3, (const unsigned short*)xb4, wfh, wfl, bias, out);
}

// Round 15
// 587.209 us; speedup vs baseline: 1.0672x; 1.0672x over previous
//
#include <hip/hip_runtime.h>

#define V 196608
#define NNZ (9 * V)
#define B 4
#define FIN 32
#define FOUT 64
#define K 5
#define C 128            // FIN*B feature columns per vertex
#define ROWU 64          // uints per bf16 row (128 feats * 2B / 4B)
#define SPMM_BLOCKS 2048 // persistent grid: 8 blocks/CU * 256 CU
#define HIST_BLOCKS (NNZ / 256)    // 6912 plain slices (dense rank writes)
#define X0_BLOCKS (V * 16 / 256)   // 12288
#define WFRAG_BLOCKS 5

typedef __attribute__((ext_vector_type(8))) short bf16x8;
typedef __attribute__((ext_vector_type(4))) float f32x4;

// ---- bf16 helpers (bit-level, RNE) ---------------------------------------
static __device__ __forceinline__ unsigned int f2bf(float f) {
    union { float f; unsigned int u; } v; v.f = f;
    return (v.u + 0x7FFFu + ((v.u >> 16) & 1u)) >> 16;
}
static __device__ __forceinline__ float bflo(unsigned int u) {
    union { unsigned int u; float f; } v; v.u = u << 16; return v.f;
}
static __device__ __forceinline__ float bfhi(unsigned int u) {
    union { unsigned int u; float f; } v; v.u = u & 0xFFFF0000u; return v.f;
}

// ---------------------------------------------------------------------------
// zero cnt8: 8*V ints = 2*V uint4 = 393216
__global__ void zero_cnt8(uint4* __restrict__ p) {
    int t = blockIdx.x * 256 + threadIdx.x;
    if (t < 2 * V) p[t] = (uint4){0u, 0u, 0u, 0u};
}

// ---------------------------------------------------------------------------
// FUSED prep. Hist: block blk handles edges [blk*256, +256) (dense rank
// writes), atomics into PRIVATE COPY cnt8[blk&7] -> with round-robin
// block->XCD dispatch each 768KB copy stays in one XCD's L2 (no cross-XCD
// line bounce; r14's windowed variant fragmented rank writes - this doesn't).
// Tail blocks: x0 transpose + W frags (independent work, one dispatch).
__global__ void prep_fused(const int* __restrict__ rows, int* __restrict__ cnt8,
                           int* __restrict__ rank, const float* __restrict__ inp,
                           uint4* __restrict__ x0v, const float* __restrict__ w,
                           uint4* __restrict__ wfh, uint4* __restrict__ wfl) {
    const int blk = blockIdx.x;
    if (blk < HIST_BLOCKS) {
        int e = blk * 256 + threadIdx.x;  // NNZ == HIST_BLOCKS*256 exactly
        int c = blk & 7;
        rank[e] = atomicAdd(&cnt8[c * V + rows[e]], 1);
    } else if (blk < HIST_BLOCKS + X0_BLOCKS) {
        // ---- x0[v][b*32+fin] bf16 b-major; thread = one uint4 (8 feats) ----
        int t = (blk - HIST_BLOCKS) * 256 + threadIdx.x;  // < V*16 exactly
        int v = t >> 4;
        int seg = t & 15;
        int b = seg >> 2;
        int q = seg & 3;
        const float4* s =
            reinterpret_cast<const float4*>(inp + ((size_t)b * V + v) * 32 + q * 8);
        float4 fa = s[0], fb = s[1];
        uint4 u;
        u.x = f2bf(fa.x) | (f2bf(fa.y) << 16);
        u.y = f2bf(fa.z) | (f2bf(fa.w) << 16);
        u.z = f2bf(fb.x) | (f2bf(fb.y) << 16);
        u.w = f2bf(fb.z) | (f2bf(fb.w) << 16);
        x0v[(size_t)v * 16 + seg] = u;
    } else {
        // ---- W fragments: split-precision bf16 B-frags, k-major ----
        int idx = (blk - HIST_BLOCKS - X0_BLOCKS) * 256 + threadIdx.x;
        if (idx >= K * 4 * 64) return;
        int lane = idx & 63;
        int nt = (idx >> 6) & 3;
        int k = idx >> 8;
        int col = lane & 15;
        int quad = lane >> 4;
        int o = nt * 16 + col;
        unsigned int hh[8], ll[8];
#pragma unroll
        for (int e = 0; e < 8; ++e) {
            int fin = quad * 8 + e;
            float wv = w[(fin * 5 + k) * 64 + o];
            unsigned int hb = f2bf(wv);
            float hf = bflo(hb);
            ll[e] = f2bf(wv - hf);
            hh[e] = hb;
        }
        uint4 uh, ul;
        uh.x = hh[0] | (hh[1] << 16);
        uh.y = hh[2] | (hh[3] << 16);
        uh.z = hh[4] | (hh[5] << 16);
        uh.w = hh[6] | (hh[7] << 16);
        ul.x = ll[0] | (ll[1] << 16);
        ul.y = ll[2] | (ll[3] << 16);
        ul.z = ll[4] | (ll[5] << 16);
        ul.w = ll[6] | (ll[7] << 16);
        wfh[idx] = uh;
        wfl[idx] = ul;
    }
}

// ---------------------------------------------------------------------------
// parallel scan phase A: per-1024-chunk sums over the 8-copy totals
__global__ void chunk_sums(const int* __restrict__ cnt8, int* __restrict__ bsum) {
    __shared__ int ws[16];
    int tid = threadIdx.x;
    int lane = tid & 63;
    int wid = tid >> 6;
    int r = blockIdx.x * 1024 + tid;
    int v = 0;
#pragma unroll
    for (int x = 0; x < 8; ++x) v += cnt8[x * V + r];
#pragma unroll
    for (int off = 32; off >= 1; off >>= 1) v += __shfl_down(v, off, 64);
    if (lane == 0) ws[wid] = v;
    __syncthreads();
    if (tid < 16) {
        int s = ws[tid];
#pragma unroll
        for (int off = 8; off >= 1; off >>= 1) s += __shfl_down(s, off, 16);
        if (tid == 0) bsum[blockIdx.x] = s;
    }
}

// ---------------------------------------------------------------------------
// scan phase B+C fused + per-row class prefix: every block scans the 192
// chunk sums in LDS, computes per-row total over the 8 copies while writing
// off8[c][r] = prefix of copies < c, then per-chunk scan -> rowptr.
__global__ void scan_chunks2(const int* __restrict__ cnt8, const int* __restrict__ bsum,
                             int* __restrict__ rowptr, int* __restrict__ off8) {
    __shared__ int sb[192];
    __shared__ int wsum[16];
    int tid = threadIdx.x;
    int lane = tid & 63;
    int wid = tid >> 6;
    if (tid < 192) sb[tid] = bsum[tid];
    __syncthreads();
    for (int off = 1; off < 192; off <<= 1) {
        int v = (tid < 192 && tid >= off) ? sb[tid - off] : 0;
        __syncthreads();
        if (tid < 192) sb[tid] += v;
        __syncthreads();
    }
    const int bpre = (blockIdx.x == 0) ? 0 : sb[blockIdx.x - 1];
    int r = blockIdx.x * 1024 + tid;
    int tot = 0;
#pragma unroll
    for (int x = 0; x < 8; ++x) {
        int cv = cnt8[x * V + r];
        off8[x * V + r] = tot;  // coalesced (consecutive r per wave)
        tot += cv;
    }
    int v = tot;
    int x = v;
#pragma unroll
    for (int off = 1; off < 64; off <<= 1) {
        int t = __shfl_up(x, off, 64);
        if (lane >= off) x += t;
    }
    if (lane == 63) wsum[wid] = x;
    __syncthreads();
    if (wid == 0 && lane < 16) {
        int s = wsum[lane];
        int y = s;
#pragma unroll
        for (int off = 1; off < 16; off <<= 1) {
            int t = __shfl_up(y, off, 16);
            if (lane >= off) y += t;
        }
        wsum[lane] = y - s;
    }
    __syncthreads();
    int excl = x - v + wsum[wid] + bpre;
    rowptr[r] = excl;
    if (blockIdx.x == 191 && tid == 1023) rowptr[V] = excl + v;
}

// ---------------------------------------------------------------------------
// rank scatter (single pass, no atomics): p = rowptr[r] + off8[class][r] +
// rank[e], class = (e>>8)&7 (the hist block's copy index, derivable from e).
__global__ void scatter_rank(const int* __restrict__ rows, const int* __restrict__ cols,
                             const float* __restrict__ vals, const int* __restrict__ rowptr,
                             const int* __restrict__ rank, const int* __restrict__ off8,
                             int2* __restrict__ cev) {
    int e = blockIdx.x * 256 + threadIdx.x;  // NNZ exact multiple of 256
    int r = rows[e];
    int c = (e >> 8) & 7;
    int p = rowptr[r] + off8[c * V + r] + rank[e];
    int2 pk;
    pk.x = cols[e];
    pk.y = __float_as_int(vals[e]);
    cev[p] = pk;
}

// ---------------------------------------------------------------------------
// bf16 gather SpMM v3.1: persistent waves, 2 rows per iteration, joint 4+4
// strip-mine (8 gathers in flight), then solo 4-strips before 2/1 drains.
template <int COMBINE>
__global__ __launch_bounds__(256) void spmm_gather(
    const int* __restrict__ rowptr, const int2* __restrict__ cev,
    const unsigned int* __restrict__ x, const unsigned int* __restrict__ xm2,
    unsigned int* __restrict__ y) {
    const int lane = threadIdx.x & 63;
    const int wid0 = (blockIdx.x * 256 + threadIdx.x) >> 6;
    const int NW = SPMM_BLOCKS * 4;  // total waves
    for (int base = wid0 * 2; base < V; base += NW * 2) {
        const int r0 = base, r1 = base + 1;
        const int s0 = rowptr[r0];
        const int e0 = rowptr[r0 + 1];
        const int e1 = rowptr[r1 + 1];  // s1 == e0
        float ax0 = 0.f, ay0 = 0.f, ax1 = 0.f, ay1 = 0.f;
        int i0 = s0, i1 = e0;
        while (e0 - i0 >= 4 && e1 - i1 >= 4) {
            int2 Ea[4], Eb[4];
#pragma unroll
            for (int j = 0; j < 4; ++j) {
                Ea[j] = cev[i0 + j];
                Eb[j] = cev[i1 + j];
            }
            unsigned int Ua[4], Ub[4];
#pragma unroll
            for (int j = 0; j < 4; ++j) {
                Ua[j] = x[(size_t)Ea[j].x * ROWU + lane];
                Ub[j] = x[(size_t)Eb[j].x * ROWU + lane];
            }
#pragma unroll
            for (int j = 0; j < 4; ++j) {
                float va = __int_as_float(Ea[j].y);
                float vb = __int_as_float(Eb[j].y);
                ax0 = fmaf(va, bflo(Ua[j]), ax0);
                ay0 = fmaf(va, bfhi(Ua[j]), ay0);
                ax1 = fmaf(vb, bflo(Ub[j]), ax1);
                ay1 = fmaf(vb, bfhi(Ub[j]), ay1);
            }
            i0 += 4;
            i1 += 4;
        }
        while (e0 - i0 >= 4) {
            int2 Ea[4];
#pragma unroll
            for (int j = 0; j < 4; ++j) Ea[j] = cev[i0 + j];
            unsigned int Ua[4];
#pragma unroll
            for (int j = 0; j < 4; ++j) Ua[j] = x[(size_t)Ea[j].x * ROWU + lane];
#pragma unroll
            for (int j = 0; j < 4; ++j) {
                float va = __int_as_float(Ea[j].y);
                ax0 = fmaf(va, bflo(Ua[j]), ax0);
                ay0 = fmaf(va, bfhi(Ua[j]), ay0);
            }
            i0 += 4;
        }
        while (e1 - i1 >= 4) {
            int2 Eb[4];
#pragma unroll
            for (int j = 0; j < 4; ++j) Eb[j] = cev[i1 + j];
            unsigned int Ub[4];
#pragma unroll
            for (int j = 0; j < 4; ++j) Ub[j] = x[(size_t)Eb[j].x * ROWU + lane];
#pragma unroll
            for (int j = 0; j < 4; ++j) {
                float vb = __int_as_float(Eb[j].y);
                ax1 = fmaf(vb, bflo(Ub[j]), ax1);
                ay1 = fmaf(vb, bfhi(Ub[j]), ay1);
            }
            i1 += 4;
        }
        for (; i0 + 2 <= e0; i0 += 2) {
            int2 a = cev[i0], b = cev[i0 + 1];
            unsigned int u0 = x[(size_t)a.x * ROWU + lane];
            unsigned int u1 = x[(size_t)b.x * ROWU + lane];
            float v0 = __int_as_float(a.y), v1 = __int_as_float(b.y);
            ax0 = fmaf(v0, bflo(u0), ax0);
            ay0 = fmaf(v0, bfhi(u0), ay0);
            ax0 = fmaf(v1, bflo(u1), ax0);
            ay0 = fmaf(v1, bfhi(u1), ay0);
        }
        for (; i0 < e0; ++i0) {
            int2 a = cev[i0];
            unsigned int u = x[(size_t)a.x * ROWU + lane];
            float v = __int_as_float(a.y);
            ax0 = fmaf(v, bflo(u), ax0);
            ay0 = fmaf(v, bfhi(u), ay0);
        }
        for (; i1 + 2 <= e1; i1 += 2) {
            int2 a = cev[i1], b = cev[i1 + 1];
            unsigned int u0 = x[(size_t)a.x * ROWU + lane];
            unsigned int u1 = x[(size_t)b.x * ROWU + lane];
            float v0 = __int_as_float(a.y), v1 = __int_as_float(b.y);
            ax1 = fmaf(v0, bflo(u0), ax1);
            ay1 = fmaf(v0, bfhi(u0), ay1);
            ax1 = fmaf(v1, bflo(u1), ax1);
            ay1 = fmaf(v1, bfhi(u1), ay1);
        }
        for (; i1 < e1; ++i1) {
            int2 a = cev[i1];
            unsigned int u = x[(size_t)a.x * ROWU + lane];
            float v = __int_as_float(a.y);
            ax1 = fmaf(v, bflo(u), ax1);
            ay1 = fmaf(v, bfhi(u), ay1);
        }
        if (COMBINE) {
            unsigned int m0 = xm2[(size_t)r0 * ROWU + lane];
            unsigned int m1 = xm2[(size_t)r1 * ROWU + lane];
            ax0 = 2.0f * ax0 - bflo(m0);
            ay0 = 2.0f * ay0 - bfhi(m0);
            ax1 = 2.0f * ax1 - bflo(m1);
            ay1 = 2.0f * ay1 - bfhi(m1);
        }
        y[(size_t)r0 * ROWU + lane] = f2bf(ax0) | (f2bf(ay0) << 16);
        y[(size_t)r1 * ROWU + lane] = f2bf(ax1) | (f2bf(ay1) << 16);
    }
}

// ---------------------------------------------------------------------------
// MFMA fused output contraction. Wave = 16 vertices x 64 outs x 4 batches.
// A-frag: lane l holds x[v0+(l&15)][b*32 + (l>>4)*8 .. +8]  (one 16B load)
// C/D:    col=lane&15, row=(lane>>4)*4+reg   [m89-verified mapping]
__global__ __launch_bounds__(256) void fused_mfma(
    const unsigned short* __restrict__ x0, const unsigned short* __restrict__ x1,
    const unsigned short* __restrict__ x2, const unsigned short* __restrict__ x3,
    const unsigned short* __restrict__ x4, const uint4* __restrict__ wfh,
    const uint4* __restrict__ wfl, const float* __restrict__ bias,
    float* __restrict__ out) {
    const int tid = threadIdx.x;
    const int lane = tid & 63;
    const int g = (blockIdx.x * 256 + tid) >> 6;
    const int v0 = g << 4;
    const int col = lane & 15;
    const int quad = lane >> 4;
    const unsigned short* const xs[K] = {x0, x1, x2, x3, x4};

    f32x4 acc[B][4];
#pragma unroll
    for (int b = 0; b < B; ++b)
#pragma unroll
        for (int nt = 0; nt < 4; ++nt) acc[b][nt] = (f32x4){0.f, 0.f, 0.f, 0.f};

#pragma unroll
    for (int k = 0; k < K; ++k) {
        const unsigned short* xk = xs[k] + ((size_t)(v0 + col)) * C + quad * 8;
        bf16x8 a0 = *reinterpret_cast<const bf16x8*>(xk);
        bf16x8 a1 = *reinterpret_cast<const bf16x8*>(xk + 32);
        bf16x8 a2 = *reinterpret_cast<const bf16x8*>(xk + 64);
        bf16x8 a3 = *reinterpret_cast<const bf16x8*>(xk + 96);
#pragma unroll
        for (int nt = 0; nt < 4; ++nt) {
            uint4 uh = wfh[(k * 4 + nt) * 64 + lane];
            uint4 ul = wfl[(k * 4 + nt) * 64 + lane];
            bf16x8 wh = *reinterpret_cast<bf16x8*>(&uh);
            bf16x8 wl = *reinterpret_cast<bf16x8*>(&ul);
            acc[0][nt] = __builtin_amdgcn_mfma_f32_16x16x32_bf16(a0, wh, acc[0][nt], 0, 0, 0);
            acc[1][nt] = __builtin_amdgcn_mfma_f32_16x16x32_bf16(a1, wh, acc[1][nt], 0, 0, 0);
            acc[2][nt] = __builtin_amdgcn_mfma_f32_16x16x32_bf16(a2, wh, acc[2][nt], 0, 0, 0);
            acc[3][nt] = __builtin_amdgcn_mfma_f32_16x16x32_bf16(a3, wh, acc[3][nt], 0, 0, 0);
            acc[0][nt] = __builtin_amdgcn_mfma_f32_16x16x32_bf16(a0, wl, acc[0][nt], 0, 0, 0);
            acc[1][nt] = __builtin_amdgcn_mfma_f32_16x16x32_bf16(a1, wl, acc[1][nt], 0, 0, 0);
            acc[2][nt] = __builtin_amdgcn_mfma_f32_16x16x32_bf16(a2, wl, acc[2][nt], 0, 0, 0);
            acc[3][nt] = __builtin_amdgcn_mfma_f32_16x16x32_bf16(a3, wl, acc[3][nt], 0, 0, 0);
        }
    }

    float bv[4];
#pragma unroll
    for (int nt = 0; nt < 4; ++nt) bv[nt] = bias[nt * 16 + col];
#pragma unroll
    for (int b = 0; b < B; ++b)
#pragma unroll
        for (int nt = 0; nt < 4; ++nt)
#pragma unroll
            for (int r = 0; r < 4; ++r) {
                int row = quad * 4 + r;
                out[((size_t)b * V + v0 + row) * FOUT + nt * 16 + col] = acc[b][nt][r] + bv[nt];
            }
}

// ---------------------------------------------------------------------------
extern "C" void kernel_launch(void* const* d_in, const int* in_sizes, int n_in,
                              void* d_out, int out_size, void* d_ws, size_t ws_size,
                              hipStream_t stream) {
    const int* lap_rows = (const int*)d_in[0];
    const int* lap_cols = (const int*)d_in[1];
    const float* lap_vals = (const float*)d_in[2];
    const float* inputs = (const float*)d_in[3];
    const float* weight = (const float*)d_in[4];  // flat [160][64] == effective W
    const float* bias = (const float*)d_in[5];
    float* out = (float*)d_out;

    char* p = (char*)d_ws;
    auto alloc = [&](size_t bytes) {
        char* r = p;
        p += (bytes + 511) & ~(size_t)511;
        return r;
    };
    int* rowptr = (int*)alloc((size_t)(V + 1) * 4);
    int* cnt8 = (int*)alloc((size_t)8 * V * 4);   // 8 per-XCD histogram copies
    int* off8 = (int*)alloc((size_t)8 * V * 4);   // per-row class prefixes
    int* bsum = (int*)alloc(192 * 4);
    int* rank = (int*)alloc((size_t)NNZ * 4);
    uint4* wfh = (uint4*)alloc((size_t)K * 4 * 64 * 16);
    uint4* wfl = (uint4*)alloc((size_t)K * 4 * 64 * 16);
    int2* cev = (int2*)alloc((size_t)NNZ * 8);
    unsigned int* xb0 = (unsigned int*)alloc((size_t)V * ROWU * 4);
    unsigned int* xb1 = (unsigned int*)alloc((size_t)V * ROWU * 4);
    unsigned int* xb2 = (unsigned int*)alloc((size_t)V * ROWU * 4);
    unsigned int* xb3 = (unsigned int*)alloc((size_t)V * ROWU * 4);
    unsigned int* xb4 = (unsigned int*)alloc((size_t)V * ROWU * 4);

    const int mfma_blocks = (V / 16) * 64 / 256; // 3072
    const int prep_blocks = HIST_BLOCKS + X0_BLOCKS + WFRAG_BLOCKS;  // 19205
    const int edge_blocks = NNZ / 256;           // 6912

    // ---- CSR build + prep ----
    zero_cnt8<<<(2 * V + 255) / 256, 256, 0, stream>>>((uint4*)cnt8);
    prep_fused<<<prep_blocks, 256, 0, stream>>>(lap_rows, cnt8, rank, inputs, (uint4*)xb0,
                                                weight, wfh, wfl);
    chunk_sums<<<V / 1024, 1024, 0, stream>>>(cnt8, bsum);
    scan_chunks2<<<V / 1024, 1024, 0, stream>>>(cnt8, bsum, rowptr, off8);
    scatter_rank<<<edge_blocks, 256, 0, stream>>>(lap_rows, lap_cols, lap_vals, rowptr,
                                                  rank, off8, cev);

    // ---- Chebyshev recurrence (bf16 storage, f32 accumulate) ----
    spmm_gather<0><<<SPMM_BLOCKS, 256, 0, stream>>>(rowptr, cev, xb0, nullptr, xb1);
    spmm_gather<1><<<SPMM_BLOCKS, 256, 0, stream>>>(rowptr, cev, xb1, xb0, xb2);
    spmm_gather<1><<<SPMM_BLOCKS, 256, 0, stream>>>(rowptr, cev, xb2, xb1, xb3);
    spmm_gather<1><<<SPMM_BLOCKS, 256, 0, stream>>>(rowptr, cev, xb3, xb2, xb4);

    // ---- fused MFMA output contraction ----
    fused_mfma<<<mfma_blocks, 256, 0, stream>>>(
        (const unsigned short*)xb0, (const unsigned short*)xb1, (const unsigned short*)xb2,
        (const unsigned short*)xb3, (const unsigned short*)xb4, wfh, wfl, bias, out);
}